// Round 10
// baseline (393.877 us; speedup 1.0000x reference)
//
#include <hip/hip_runtime.h>
#include <stdint.h>

// Binarized dense: C[r][u] = sum_k sign(x[r][k]) * sign(W[k][u]) + b[u]
//   sign(v) = +1 if v >= 0 else -1   -> bit(v) = (v < 0)
//   dot = F - 2 * popcount(xbits ^ wbits)
//
// Bit layout (verified rounds 1/3/4/5/7/8/9): u64 word w = c*4 + j for chunk
// c (256 floats) and float4 component j; bit i = ballot lane i, i.e. element
// k = c*256 + i*4 + j. In-chunk u32 words w32 = 0..7 map to
// (b0.lo,b0.hi,b1.lo,b1.hi,b2.lo,b2.hi,b3.lo,b3.hi), halves h = w32>>2.
//
// v4 design: NO LDS, NO barriers. Each wave owns 4 rows x 512 cols.
//  - x-bits: __ballot results are wave-uniform -> live in SGPRs (xb[4][4]).
//  - W-bits: re-laid out chunk-major by pack_w so each lane's per-half
//    fragment is ONE coalesced uint4 from L2 (Wp2 is 256 KB, L2-resident).
//    Wq[(c*2+h)*512 + u] = u32 words c*8+4h .. +3 of column u.
//  - per chunk: issue x(c+1) -> compute h0 (wvA) -> reload wvA=(c+1,h0)
//    -> compute h1 (wvB) -> reload wvB=(c+1,h1), ballot x(c+1).
//    Compiler-inserted vmcnt waits; loads stay in flight under ~500-inst
//    compute windows. Waves free-run: no lockstep stalls.
//  - acc packed 2xu16 (sums <= 4096, exact): 16 VGPRs.
// VGPR ~115 (wvA 32 + wvB 32 + xr 16 + acc 16 + addr) -> 4 waves/SIMD;
// 1024 blocks x 256 thr = 4096 waves = exactly resident on 256 CUs.

#define BATCH  16384
#define INF    4096
#define UNITS  512
#define KW     128      // u32 words per row (4096/32)
#define NCH    16       // K-chunks of 256 floats (8 u32 words)

// ------ pack W: [4096,512] f32 -> Wp2 chunk-major uint4 tiles (256 KB) ------
__global__ __launch_bounds__(256) void pack_w_kernel(const float* __restrict__ W,
                                                     uint32_t* __restrict__ Wp2) {
    int t  = blockIdx.x * 256 + threadIdx.x;   // 0..32767
    int u  = t & 511;                          // column
    int cj = t >> 9;                           // 0..63 = c*4 + j
    int j  = cj & 3;
    int c  = cj >> 2;
    const float* base = W + (size_t)(c * 256 + j) * UNITS + u;
    unsigned long long m = 0;
    #pragma unroll 16
    for (int i = 0; i < 64; ++i) {
        // element k = c*256 + 4*i + j ; bit i matches ballot lane i
        float v = base[(size_t)(4 * i) * UNITS];
        m |= (unsigned long long)(v < 0.f) << i;
    }
    // u32 words 2j (lo), 2j+1 (hi) of chunk c -> half h = j>>1, word 2*(j&1)
    uint32_t* dst = Wp2 + ((size_t)(c * 2 + (j >> 1)) * 512 + u) * 4 + 2 * (j & 1);
    *reinterpret_cast<uint2*>(dst) = make_uint2((uint32_t)m, (uint32_t)(m >> 32));
}

// ------------------------------ fused kernel --------------------------------
__global__ __launch_bounds__(256, 4) void fused_kernel(const float* __restrict__ x,
                                                       const uint32_t* __restrict__ Wp2,
                                                       const float* __restrict__ bias,
                                                       float* __restrict__ C) {
    const int t  = threadIdx.x;
    const int l  = t & 63;
    const int gw = (blockIdx.x * 256 + t) >> 6;   // global wave 0..4095
    const int row0 = gw * 4;
    const float4* xf4 = reinterpret_cast<const float4*>(x);
    const uint4*  Wq  = reinterpret_cast<const uint4*>(Wp2);

    uint32_t acc[4][4] = {};            // lo16: col l+64jj, hi16: col +256
    unsigned long long xb[4][4];        // wave-uniform ballots (SGPR pairs)
    float4 xr[4];
    uint4  wvA[8], wvB[8];

    // ---- prologue: issue x(0), W(0,h0)->wvA, W(0,h1)->wvB; ballot x(0) ----
    #pragma unroll
    for (int i = 0; i < 4; ++i)
        xr[i] = xf4[((size_t)(row0 + i) << 10) + l];
    #pragma unroll
    for (int jj = 0; jj < 8; ++jj)
        wvA[jj] = Wq[(size_t)(jj * 64 + l)];
    #pragma unroll
    for (int jj = 0; jj < 8; ++jj)
        wvB[jj] = Wq[(size_t)512 + jj * 64 + l];
    #pragma unroll
    for (int i = 0; i < 4; ++i) {
        xb[i][0] = __ballot(xr[i].x < 0.f);
        xb[i][1] = __ballot(xr[i].y < 0.f);
        xb[i][2] = __ballot(xr[i].z < 0.f);
        xb[i][3] = __ballot(xr[i].w < 0.f);
    }

    #pragma unroll 1
    for (int c = 0; c < NCH; ++c) {
        const bool pf = (c + 1 < NCH);

        // issue next x loads (HBM) -- in flight for the whole chunk
        if (pf) {
            #pragma unroll
            for (int i = 0; i < 4; ++i)
                xr[i] = xf4[((size_t)(row0 + i) << 10) + (size_t)(c + 1) * 64 + l];
        }

        // ---- compute half 0 (words c*8..c*8+3) from wvA ----
        #pragma unroll
        for (int i = 0; i < 4; ++i) {
            uint32_t x0 = (uint32_t)xb[i][0], x1 = (uint32_t)(xb[i][0] >> 32);
            uint32_t x2 = (uint32_t)xb[i][1], x3 = (uint32_t)(xb[i][1] >> 32);
            #pragma unroll
            for (int jj = 0; jj < 4; ++jj) {
                uint32_t lo = __popc(x0 ^ wvA[jj].x) + __popc(x1 ^ wvA[jj].y)
                            + __popc(x2 ^ wvA[jj].z) + __popc(x3 ^ wvA[jj].w);
                uint32_t hi = __popc(x0 ^ wvA[jj + 4].x) + __popc(x1 ^ wvA[jj + 4].y)
                            + __popc(x2 ^ wvA[jj + 4].z) + __popc(x3 ^ wvA[jj + 4].w);
                acc[i][jj] += lo + (hi << 16);
            }
        }
        // reload wvA with (c+1, h0) -- consumed next iteration
        if (pf) {
            #pragma unroll
            for (int jj = 0; jj < 8; ++jj)
                wvA[jj] = Wq[(size_t)(c * 2 + 2) * 512 + jj * 64 + l];
        }

        // ---- compute half 1 (words c*8+4..c*8+7) from wvB ----
        #pragma unroll
        for (int i = 0; i < 4; ++i) {
            uint32_t x4 = (uint32_t)xb[i][2], x5 = (uint32_t)(xb[i][2] >> 32);
            uint32_t x6 = (uint32_t)xb[i][3], x7 = (uint32_t)(xb[i][3] >> 32);
            #pragma unroll
            for (int jj = 0; jj < 4; ++jj) {
                uint32_t lo = __popc(x4 ^ wvB[jj].x) + __popc(x5 ^ wvB[jj].y)
                            + __popc(x6 ^ wvB[jj].z) + __popc(x7 ^ wvB[jj].w);
                uint32_t hi = __popc(x4 ^ wvB[jj + 4].x) + __popc(x5 ^ wvB[jj + 4].y)
                            + __popc(x6 ^ wvB[jj + 4].z) + __popc(x7 ^ wvB[jj + 4].w);
                acc[i][jj] += lo + (hi << 16);
            }
        }
        // reload wvB with (c+1, h1); ballot-pack the in-flight x(c+1)
        if (pf) {
            #pragma unroll
            for (int jj = 0; jj < 8; ++jj)
                wvB[jj] = Wq[(size_t)(c * 2 + 3) * 512 + jj * 64 + l];
            #pragma unroll
            for (int i = 0; i < 4; ++i) {
                xb[i][0] = __ballot(xr[i].x < 0.f);
                xb[i][1] = __ballot(xr[i].y < 0.f);
                xb[i][2] = __ballot(xr[i].z < 0.f);
                xb[i][3] = __ballot(xr[i].w < 0.f);
            }
        }
    }

    // ---- epilogue: unpack u16 halves, C = INF - 2*acc + bias ----
    #pragma unroll
    for (int jj = 0; jj < 4; ++jj) {
        const int u0 = l + 64 * jj, u1 = u0 + 256;
        const float b0 = bias[u0], b1 = bias[u1];
        #pragma unroll
        for (int i = 0; i < 4; ++i) {
            size_t r = (size_t)(row0 + i) * UNITS;
            uint32_t pk = acc[i][jj];
            C[r + u0] = (float)(INF - 2 * (int)(pk & 0xFFFFu)) + b0;
            C[r + u1] = (float)(INF - 2 * (int)(pk >> 16)) + b1;
        }
    }
}

extern "C" void kernel_launch(void* const* d_in, const int* in_sizes, int n_in,
                              void* d_out, int out_size, void* d_ws, size_t ws_size,
                              hipStream_t stream) {
    const float* x = (const float*)d_in[0];
    const float* W = (const float*)d_in[1];
    const float* b = (const float*)d_in[2];
    float* out = (float*)d_out;

    uint32_t* Wp2 = (uint32_t*)d_ws;   // 256 KB, chunk-major packed W

    pack_w_kernel<<<32768 / 256, 256, 0, stream>>>(W, Wp2);
    fused_kernel<<<BATCH / 16, 256, 0, stream>>>(x, Wp2, b, out);
}

// Round 11
// 105.144 us; speedup vs baseline: 3.7461x; 3.7461x over previous
//
#include <hip/hip_runtime.h>
#include <stdint.h>

// Binarized dense: C[r][u] = sum_k sign(x[r][k]) * sign(W[k][u]) + b[u]
//   sign(v) = +1 if v >= 0 else -1   -> bit(v) = (v < 0)
//   dot = F - 2 * popcount(xbits ^ wbits)
//
// Bit layout (verified rounds 1/3/4/5/7/8/9/10): u64 word w = c*4 + j for
// chunk c (256 floats) and float4 component j; bit i = ballot lane i, i.e.
// element k = c*256 + i*4 + j. In-chunk u32 words 0..7 =
// (b0.lo,b0.hi,b1.lo,b1.hi,b2.lo,b2.hi,b3.lo,b3.hi), halves h = word>>2.
//
// v5 = v4 free-running design re-hosted in 512-thread blocks.
// Round-10 failure: 256-thread blocks -> allocator targets 64 VGPRs ->
// wvA/wvB (64 regs) went to scratch (WRITE 804 MB). 512-thread blocks
// empirically get a 128-VGPR cap with alloc-to-demand (round 8: 112).
// Demand here ~108: wvA 32 + wvB 32 + xr 16 + acc 16 + addr.
//  - NO LDS, NO barriers; each wave owns 4 rows x 512 cols, free-runs.
//  - x-bits wave-uniform in SGPRs via __ballot; x read from HBM once.
//  - W chunk-major (Wq[(c*2+h)*512+u]): each lane's fragment = coalesced
//    uint4 from L2 (256 KB resident; ~16KB/chunk-half also L1-friendly).
//  - Prefetch is UNCONDITIONAL with the chunk index clamped to the last
//    chunk (avoids conditional array PHIs that can demote arrays to
//    scratch; extra reads of chunk 15 are L1/L2 hits, harmless).
// Grid 512 x 512thr = 4096 waves = 2 blocks/CU at 4 waves/SIMD, exactly
// resident.

#define BATCH  16384
#define INF    4096
#define UNITS  512
#define KW     128      // u32 words per row (4096/32)
#define NCH    16       // K-chunks of 256 floats (8 u32 words)

// ------ pack W: [4096,512] f32 -> Wp2 chunk-major uint4 tiles (256 KB) ------
__global__ __launch_bounds__(256) void pack_w_kernel(const float* __restrict__ W,
                                                     uint32_t* __restrict__ Wp2) {
    int t  = blockIdx.x * 256 + threadIdx.x;   // 0..32767
    int u  = t & 511;                          // column
    int cj = t >> 9;                           // 0..63 = c*4 + j
    int j  = cj & 3;
    int c  = cj >> 2;
    const float* base = W + (size_t)(c * 256 + j) * UNITS + u;
    unsigned long long m = 0;
    #pragma unroll 16
    for (int i = 0; i < 64; ++i) {
        // element k = c*256 + 4*i + j ; bit i matches ballot lane i
        float v = base[(size_t)(4 * i) * UNITS];
        m |= (unsigned long long)(v < 0.f) << i;
    }
    // u32 words 2j (lo), 2j+1 (hi) of chunk c -> half h = j>>1, word 2*(j&1)
    uint32_t* dst = Wp2 + ((size_t)(c * 2 + (j >> 1)) * 512 + u) * 4 + 2 * (j & 1);
    *reinterpret_cast<uint2*>(dst) = make_uint2((uint32_t)m, (uint32_t)(m >> 32));
}

// ------------------------------ fused kernel --------------------------------
__global__ __launch_bounds__(512, 1) void fused_kernel(const float* __restrict__ x,
                                                       const uint32_t* __restrict__ Wp2,
                                                       const float* __restrict__ bias,
                                                       float* __restrict__ C) {
    const int t  = threadIdx.x;
    const int l  = t & 63;
    const int gw = (blockIdx.x * 512 + t) >> 6;   // global wave 0..4095
    const int row0 = gw * 4;
    const float4* xf4 = reinterpret_cast<const float4*>(x);
    const uint4*  Wq  = reinterpret_cast<const uint4*>(Wp2);

    uint32_t acc[4][4] = {};            // lo16: col l+64jj, hi16: col +256
    unsigned long long xb[4][4];        // wave-uniform ballots (SGPR pairs)
    float4 xr[4];
    uint4  wvA[8], wvB[8];

    // ---- prologue: issue x(0), W(0,h0)->wvA, W(0,h1)->wvB; ballot x(0) ----
    #pragma unroll
    for (int i = 0; i < 4; ++i)
        xr[i] = xf4[((size_t)(row0 + i) << 10) + l];
    #pragma unroll
    for (int jj = 0; jj < 8; ++jj)
        wvA[jj] = Wq[(size_t)(jj * 64 + l)];
    #pragma unroll
    for (int jj = 0; jj < 8; ++jj)
        wvB[jj] = Wq[(size_t)512 + jj * 64 + l];
    #pragma unroll
    for (int i = 0; i < 4; ++i) {
        xb[i][0] = __ballot(xr[i].x < 0.f);
        xb[i][1] = __ballot(xr[i].y < 0.f);
        xb[i][2] = __ballot(xr[i].z < 0.f);
        xb[i][3] = __ballot(xr[i].w < 0.f);
    }

    #pragma unroll 1
    for (int c = 0; c < NCH; ++c) {
        // clamped next-chunk index: unconditional prefetch, no array PHIs
        const int cn = (c + 1 < NCH) ? (c + 1) : (NCH - 1);

        // issue next x loads (HBM) -- in flight for the whole chunk
        #pragma unroll
        for (int i = 0; i < 4; ++i)
            xr[i] = xf4[((size_t)(row0 + i) << 10) + (size_t)cn * 64 + l];

        // ---- compute half 0 (words c*8..c*8+3) from wvA ----
        #pragma unroll
        for (int i = 0; i < 4; ++i) {
            uint32_t x0 = (uint32_t)xb[i][0], x1 = (uint32_t)(xb[i][0] >> 32);
            uint32_t x2 = (uint32_t)xb[i][1], x3 = (uint32_t)(xb[i][1] >> 32);
            #pragma unroll
            for (int jj = 0; jj < 4; ++jj) {
                uint32_t lo = __popc(x0 ^ wvA[jj].x) + __popc(x1 ^ wvA[jj].y)
                            + __popc(x2 ^ wvA[jj].z) + __popc(x3 ^ wvA[jj].w);
                uint32_t hi = __popc(x0 ^ wvA[jj + 4].x) + __popc(x1 ^ wvA[jj + 4].y)
                            + __popc(x2 ^ wvA[jj + 4].z) + __popc(x3 ^ wvA[jj + 4].w);
                acc[i][jj] += lo + (hi << 16);
            }
        }
        // reload wvA with (cn, h0) -- consumed next iteration
        #pragma unroll
        for (int jj = 0; jj < 8; ++jj)
            wvA[jj] = Wq[(size_t)(cn * 2) * 512 + jj * 64 + l];

        // ---- compute half 1 (words c*8+4..c*8+7) from wvB ----
        #pragma unroll
        for (int i = 0; i < 4; ++i) {
            uint32_t x4 = (uint32_t)xb[i][2], x5 = (uint32_t)(xb[i][2] >> 32);
            uint32_t x6 = (uint32_t)xb[i][3], x7 = (uint32_t)(xb[i][3] >> 32);
            #pragma unroll
            for (int jj = 0; jj < 4; ++jj) {
                uint32_t lo = __popc(x4 ^ wvB[jj].x) + __popc(x5 ^ wvB[jj].y)
                            + __popc(x6 ^ wvB[jj].z) + __popc(x7 ^ wvB[jj].w);
                uint32_t hi = __popc(x4 ^ wvB[jj + 4].x) + __popc(x5 ^ wvB[jj + 4].y)
                            + __popc(x6 ^ wvB[jj + 4].z) + __popc(x7 ^ wvB[jj + 4].w);
                acc[i][jj] += lo + (hi << 16);
            }
        }
        // reload wvB with (cn, h1); ballot-pack the in-flight x(cn)
        #pragma unroll
        for (int jj = 0; jj < 8; ++jj)
            wvB[jj] = Wq[(size_t)(cn * 2 + 1) * 512 + jj * 64 + l];
        #pragma unroll
        for (int i = 0; i < 4; ++i) {
            xb[i][0] = __ballot(xr[i].x < 0.f);
            xb[i][1] = __ballot(xr[i].y < 0.f);
            xb[i][2] = __ballot(xr[i].z < 0.f);
            xb[i][3] = __ballot(xr[i].w < 0.f);
        }
    }

    // ---- epilogue: unpack u16 halves, C = INF - 2*acc + bias ----
    #pragma unroll
    for (int jj = 0; jj < 4; ++jj) {
        const int u0 = l + 64 * jj, u1 = u0 + 256;
        const float b0 = bias[u0], b1 = bias[u1];
        #pragma unroll
        for (int i = 0; i < 4; ++i) {
            size_t r = (size_t)(row0 + i) * UNITS;
            uint32_t pk = acc[i][jj];
            C[r + u0] = (float)(INF - 2 * (int)(pk & 0xFFFFu)) + b0;
            C[r + u1] = (float)(INF - 2 * (int)(pk >> 16)) + b1;
        }
    }
}

extern "C" void kernel_launch(void* const* d_in, const int* in_sizes, int n_in,
                              void* d_out, int out_size, void* d_ws, size_t ws_size,
                              hipStream_t stream) {
    const float* x = (const float*)d_in[0];
    const float* W = (const float*)d_in[1];
    const float* b = (const float*)d_in[2];
    float* out = (float*)d_out;

    uint32_t* Wp2 = (uint32_t*)d_ws;   // 256 KB, chunk-major packed W

    pack_w_kernel<<<32768 / 256, 256, 0, stream>>>(W, Wp2);
    fused_kernel<<<BATCH / 32, 512, 0, stream>>>(x, Wp2, b, out);
}